// Round 16
// baseline (594.005 us; speedup 1.0000x reference)
//
#include <hip/hip_runtime.h>
#include <hip/hip_bf16.h>

// Problem constants
constexpr int BATCH = 8;
constexpr int CH    = 256;
constexpr int H     = 96;
constexpr int W     = 96;
constexpr int HW    = H * W;                         // 9216
constexpr long PLANE_ELEMS = (long)BATCH * CH * HW;  // 18,874,368
constexpr int PAD   = 98;                            // padded spatial dim

typedef short  bf16x8_t __attribute__((ext_vector_type(8)));
typedef float  f32x4_t  __attribute__((ext_vector_type(4)));

__device__ inline uint pk2_bf16(float a, float b) {
  ushort lo = __bfloat16_as_ushort(__float2bfloat16(a));
  ushort hi = __bfloat16_as_ushort(__float2bfloat16(b));
  return (uint)lo | ((uint)hi << 16);
}

#define WAITVM(N) asm volatile("s_waitcnt vmcnt(" #N ")" ::: "memory")

__device__ __forceinline__ void gl_lds16(const ushort* g, ushort* l) {
  __builtin_amdgcn_global_load_lds(
      (const __attribute__((address_space(1))) void*)g,
      (__attribute__((address_space(3))) void*)l, 16, 0, 0);
}

// ---------------------------------------------------------------------------
// Fused prep: weights (4 tensors OIHW f32 -> fragment-linear bf16, 16x16
// layout) + border zeroing of the two padded NHWC buffers.
// Weight layout: idx = ((((tap*8+cc)*16+q)*16+l15)*4+lg)*8+e,
//   co = q*16+l15, ci = cc*32+lg*8+e  -> A-fragment load = contiguous 1KB.
// ---------------------------------------------------------------------------
__global__ __launch_bounds__(256) void prep_wb(
    const float* __restrict__ s0, const float* __restrict__ s1,
    const float* __restrict__ s2, const float* __restrict__ s3,
    ushort* __restrict__ d0, ushort* __restrict__ d1,
    ushort* __restrict__ d2, ushort* __restrict__ d3,
    ushort* __restrict__ p0, ushort* __restrict__ p1)
{
  if (blockIdx.x < 9216) {
    const int t = blockIdx.x / 2304;
    const int idx = (blockIdx.x % 2304) * 256 + threadIdx.x;
    const float* s = (t == 0) ? s0 : (t == 1) ? s1 : (t == 2) ? s2 : s3;
    ushort* d      = (t == 0) ? d0 : (t == 1) ? d1 : (t == 2) ? d2 : d3;
    const int e   = idx & 7;
    const int lg  = (idx >> 3) & 3;
    const int l15 = (idx >> 5) & 15;
    const int q   = (idx >> 9) & 15;
    const int cc  = (idx >> 13) & 7;
    const int tap = idx >> 16;
    const int co  = q * 16 + l15;
    const int ci  = cc * 32 + lg * 8 + e;
    d[idx] = __bfloat16_as_ushort(__float2bfloat16(s[(co * 256 + ci) * 9 + tap]));
    return;
  }
  const int bb = blockIdx.x - 9216;        // 0..783 = (49 u-blocks, 8 b, 2 t)
  const int ub = bb % 49;
  const int b  = (bb / 49) & 7;
  ushort* p = (bb >= 392) ? p1 : p0;
  const int u = ub * 256 + threadIdx.x;
  if (u >= 12416) return;
  int y, x, cu;
  if (u < 6272)      { y = (u < 3136) ? 0 : 97; int r = u % 3136; x = r >> 5; cu = r & 31; }
  else               { int r = u - 6272; x = (r < 3072) ? 0 : 97; int r2 = r % 3072; y = 1 + (r2 >> 5); cu = r2 & 31; }
  int4 z = make_int4(0, 0, 0, 0);
  *(int4*)&p[(((long)b * PAD + y) * PAD + x) * 256 + cu * 8] = z;
}

// ---------------------------------------------------------------------------
// Fused NCHW fp32 -> padded NHWC bf16 for feats & graph.
// grid (288, 8, 16): z>>3 selects tensor, z&7 = batch.
// ---------------------------------------------------------------------------
__global__ __launch_bounds__(256) void nchw_f32_to_nhwc_bf16_2(
    const float* __restrict__ in0, const float* __restrict__ in1,
    ushort* __restrict__ out0, ushort* __restrict__ out1)
{
  __shared__ float t[32][33];
  const int tid = threadIdx.x;
  const int p0 = blockIdx.x * 32;
  const int c0 = blockIdx.y * 32;
  const int ts = blockIdx.z >> 3;
  const int b  = blockIdx.z & 7;
  const float* in = ts ? in1 : in0;
  ushort* out     = ts ? out1 : out0;
  const int tp = tid & 31, tc8 = tid >> 5;
#pragma unroll
  for (int i = 0; i < 4; ++i) {
    int c = tc8 + i * 8;
    t[c][tp] = in[((long)(b * 256 + c0 + c)) * HW + p0 + tp];
  }
  __syncthreads();
  const int wc = tid & 31, wp8 = tid >> 5;
#pragma unroll
  for (int i = 0; i < 4; ++i) {
    int p = p0 + wp8 + i * 8;
    int y = p / 96, x = p % 96;
    out[(((long)b * PAD + y + 1) * PAD + x + 1) * 256 + c0 + wc] =
        __bfloat16_as_ushort(__float2bfloat16(t[wc][wp8 + i * 8]));
  }
}

// ---------------------------------------------------------------------------
// NCHW bf16 -> padded NHWC bf16 (fused attention output feeding conv O).
// ---------------------------------------------------------------------------
__global__ __launch_bounds__(256) void nchw_bf16_to_nhwc_bf16(
    const ushort* __restrict__ in, ushort* __restrict__ out)
{
  __shared__ ushort t[32][34];
  const int tid = threadIdx.x;
  const int p0 = blockIdx.x * 32;
  const int c0 = blockIdx.y * 32;
  const int b  = blockIdx.z;
  const int tp = tid & 31, tc8 = tid >> 5;
#pragma unroll
  for (int i = 0; i < 4; ++i) {
    int c = tc8 + i * 8;
    t[c][tp] = in[((long)(b * 256 + c0 + c)) * HW + p0 + tp];
  }
  __syncthreads();
  const int wc = tid & 31, wp8 = tid >> 5;
#pragma unroll
  for (int i = 0; i < 4; ++i) {
    int p = p0 + wp8 + i * 8;
    int y = p / 96, x = p % 96;
    out[(((long)b * PAD + y + 1) * PAD + x + 1) * 256 + c0 + wc] = t[wc][wp8 + i * 8];
  }
}

// ---------------------------------------------------------------------------
// Conv 3x3 SAME via bf16 MFMA — R16: TAIL-FREE GRID. R11's proven structure
// (16x16 MFMA, 3-slot A reg rotation, gl_lds double-buffered B, counted
// vmcnt ledger) repackaged as 512-thread blocks at 1 block/CU:
//   QKV: 2304 blocks / 256 CUs = 9.0 integral rounds (was 4.5 -> ~11% tail)
//   O:    768 blocks / 256 CUs = 3.0 integral rounds (was 1.5 -> ~33% tail)
// 8 waves of 64co x 48px (wm co-half, wx x-half, wn row). acc = 4x3 f32x4
// = 48 regs; total unified ~135 << 256 cap at (512,2) -> no spill possible.
// Same waves/CU (8) as R11, same LDS (50KB), same swizzles.
// Ledger: prologue WAITVM(8); boundary WAITVM(36) = [IN x4][A x36].
// ---------------------------------------------------------------------------
template <int NT, typename OutT>
__global__ __launch_bounds__(512, 2) void conv3x3_mfma(
    const ushort* pin0, const ushort* pin1,
    const ushort* w0, const ushort* w1, const ushort* w2,
    const float* bias0, const float* bias1, const float* bias2,
    OutT* o0, OutT* o1, OutT* o2)
{
  const int tid  = threadIdx.x;
  const int lane = tid & 63;
  const int wv   = tid >> 6;      // 0..7
  const int wm   = wv & 1;        // co half (64 co)
  const int wx   = (wv >> 1) & 1; // x half (48 px)
  const int wn   = wv >> 2;       // row within 2-row tile
  const int l15  = lane & 15;
  const int lg   = lane >> 4;

  // Bijective XCD swizzle over NT*768 blocks (divisible by 8).
  const int nwg = NT * 768;
  const int cpx = nwg >> 3;
  const int swz = ((int)blockIdx.x & 7) * cpx + ((int)blockIdx.x >> 3);
  const int t    = swz / 768;
  const int rest = swz % 768;
  const ushort* pin = (t == 2) ? pin1 : pin0;
  const ushort* wt  = (t == 0) ? w0 : (t == 1) ? w1 : w2;
  const float* bias = (t == 0) ? bias0 : (t == 1) ? bias1 : bias2;
  OutT* out         = (t == 0) ? o0 : (t == 1) ? o1 : o2;

  const int cox = rest & 1;
  const int yb  = (rest >> 1) % 48;
  const int b   = (rest >> 1) / 48;
  const int co0 = cox * 128;
  const int y0  = yb * 2;
  const int coq = cox * 8 + wm * 4;       // co/16 fragment base for this wave
  const int alo = (l15 * 4 + lg) << 3;    // per-lane elem offset in A fragment

  __shared__ ushort sIn[2][1568 * 8];     // 2 x 25,088 B (4rr x 98xx x 32ci)

  f32x4_t acc[4][3];
#pragma unroll
  for (int m = 0; m < 4; ++m)
#pragma unroll
    for (int n = 0; n < 3; ++n)
      acc[m][n] = (f32x4_t){0.f, 0.f, 0.f, 0.f};

  // Stage packed 25KB input tile (ci-chunk cc) into buf cc&1 via gl_lds.
  // 1568 units over 8 waves: 196/wave, 4 gl_lds per thread (last partial).
  auto issueIN = [&](int cc) {
    const int ci0 = cc * 32;
    const int ubase = wv * 196;
#pragma unroll
    for (int it = 0; it < 4; ++it) {
      int lo = it * 64 + lane;
      if (lo < 196) {
        int u  = ubase + lo;
        int q  = u >> 2;
        int g  = u & 3;
        int xx = q % 98, rr = q / 98;
        int ug = g ^ ((xx + (xx >> 2)) & 3);        // pre-swizzled source
        const ushort* src = pin + (((long)(b * PAD + y0 + rr)) * PAD + xx) * 256 + ci0 + ug * 8;
        ushort* dst = (ushort*)((char*)&sIn[cc & 1][0] + (long)u * 16);
        gl_lds16(src, dst);
      }
    }
  };

  // Coalesced A-fragment register load (L1/L2-resident weights).
  auto glda = [&](int tap, int cc, int m) -> bf16x8_t {
    return *(const bf16x8_t*)&wt[(((tap * 8 + cc) * 16 + coq + m) << 9) + alo];
  };

  bf16x8_t a0[4], a1[4], a2[4];   // 3-slot rotation; tap t consumes slot t%3

#define ISSUE_A(CC, TAP, AR)                \
  if ((CC) < 8) {                           \
    AR[0] = glda((TAP), (CC), 0);           \
    AR[1] = glda((TAP), (CC), 1);           \
    AR[2] = glda((TAP), (CC), 2);           \
    AR[3] = glda((TAP), (CC), 3);           \
  }

  auto dotap = [&](int DY, int DX, int bi, const bf16x8_t* a) {
    bf16x8_t bb[3];
    const char* Bb = (const char*)&sIn[bi][0];
    const int s    = l15 + DX;
    // Swizzle invariant under +16k x-offsets (wx*48, n*16) -> boff from s only.
    const int boff = (lg ^ ((s + (s >> 2)) & 3)) << 4;
    const int rr   = wn + DY;
#pragma unroll
    for (int n = 0; n < 3; ++n)
      bb[n] = *(const bf16x8_t*)(Bb + ((rr * 98 + wx * 48 + n * 16 + s) << 6) + boff);
    __builtin_amdgcn_s_setprio(1);
#pragma unroll
    for (int m = 0; m < 4; ++m)
#pragma unroll
      for (int n = 0; n < 3; ++n)
        acc[m][n] = __builtin_amdgcn_mfma_f32_16x16x32_bf16(
            a[m], bb[n], acc[m][n], 0, 0, 0);
    __builtin_amdgcn_s_setprio(0);
  };

  // Prologue: IN(0) [4] then A(0,0),A(0,1) [8] -> WAITVM(8) drains IN only.
  issueIN(0);
  __builtin_amdgcn_sched_barrier(0);
  ISSUE_A(0, 0, a0);
  ISSUE_A(0, 1, a1);
  __builtin_amdgcn_sched_barrier(0);
  WAITVM(8);
  __builtin_amdgcn_s_barrier();
  __builtin_amdgcn_sched_barrier(0);

#pragma unroll 1
  for (int c = 0; c < 8; ++c) {
    const int bi = c & 1;
    // Full-chunk-early IN prefetch (register-neutral: gl_lds holds no VGPRs).
    if (c < 7) issueIN(c + 1);
    __builtin_amdgcn_sched_barrier(0);
    // Taps flow barrier-free: A deps are register loads (compiler-tracked),
    // B deps are lgkmcnt ds_reads on a chunk-stable buffer.
    ISSUE_A(c, 2, a2)  dotap(0, 0, bi, a0);
    ISSUE_A(c, 3, a0)  dotap(0, 1, bi, a1);
    ISSUE_A(c, 4, a1)  dotap(0, 2, bi, a2);
    ISSUE_A(c, 5, a2)  dotap(1, 0, bi, a0);
    ISSUE_A(c, 6, a0)  dotap(1, 1, bi, a1);
    ISSUE_A(c, 7, a1)  dotap(1, 2, bi, a2);
    ISSUE_A(c, 8, a2)  dotap(2, 0, bi, a0);
    ISSUE_A(c + 1, 0, a0)  dotap(2, 1, bi, a1);
    ISSUE_A(c + 1, 1, a1)  dotap(2, 2, bi, a2);
    __builtin_amdgcn_sched_barrier(0);
    // Ledger: FIFO = [IN(c+1) x4][A(c,2..8)=28][A(c+1,0..1)=8] -> 36 A's.
    if (c < 7) { WAITVM(36); } else { WAITVM(0); }
    __builtin_amdgcn_s_barrier();     // all waves' IN writes visible
    __builtin_amdgcn_sched_barrier(0);
  }
#undef ISSUE_A

  // Epilogue. C/D layout: col = lane&15 -> pixel, row (lg*4+r) -> co.
  // Wave region: co [wm*64,+64) x (row wn, x [wx*48,+48)) -- disjoint.
  if constexpr (sizeof(OutT) == 2) {
    // bf16: single-pass bounce: 128 co x 392B pitch = 50,176 B (= all sIn).
    char* sE = (char*)&sIn[0][0];
#pragma unroll
    for (int m = 0; m < 4; ++m)
#pragma unroll
      for (int r = 0; r < 4; ++r) {
        const int col = wm * 64 + m * 16 + lg * 4 + r;
        const float bv = bias[co0 + col];
#pragma unroll
        for (int n = 0; n < 3; ++n) {
          *(ushort*)(sE + col * 392 + (wn * 96 + wx * 48 + n * 16 + l15) * 2) =
              __bfloat16_as_ushort(__float2bfloat16(acc[m][n][r] + bv));
        }
      }
    __syncthreads();
    // 3072 units = 128 co x 24 x 16B, fully coalesced global stores.
#pragma unroll
    for (int it = 0; it < 6; ++it) {
      int u = it * 512 + tid;
      int co = u / 24, ru = u % 24;
      int4 v = *(const int4*)(sE + co * 392 + ru * 16);
      int e0 = ru * 8;
      int yy = y0 + (e0 >= 96);
      int x  = e0 - (e0 >= 96 ? 96 : 0);
      *(int4*)&out[(((long)(b * 256 + co0 + co)) * 96 + yy) * 96 + x] = v;
    }
  } else {
    // f32: two 64-co halves, 64 co x 196-f32 pitch = 50,176 B each.
    char* sE = (char*)&sIn[0][0];
#pragma unroll
    for (int h = 0; h < 2; ++h) {
      if (wm == h) {
#pragma unroll
        for (int m = 0; m < 4; ++m)
#pragma unroll
          for (int r = 0; r < 4; ++r) {
            const int col = m * 16 + lg * 4 + r;
            const float bv = bias[co0 + h * 64 + col];
#pragma unroll
            for (int n = 0; n < 3; ++n) {
              *(float*)(sE + (col * 196 + wn * 96 + wx * 48 + n * 16 + l15) * 4) =
                  acc[m][n][r] + bv;
            }
          }
      }
      __syncthreads();
#pragma unroll
      for (int it = 0; it < 6; ++it) {
        int u = it * 512 + tid;
        int co = u / 48, ru = u % 48;
        int4 v = *(const int4*)(sE + (co * 196 + ru * 4) * 4);
        int e0 = ru * 4;
        int yy = y0 + (e0 >= 96);
        int x  = e0 - (e0 >= 96 ? 96 : 0);
        *(int4*)&out[(((long)(b * 256 + co0 + h * 64 + co)) * 96 + yy) * 96 + x] = v;
      }
      __syncthreads();
    }
  }
}

// ---------------------------------------------------------------------------
// MFMA row attention. One block (384 thr = 6 waves) per (b,c) plane.
// ---------------------------------------------------------------------------
constexpr int APITCH = 104;

__global__ __launch_bounds__(384, 3) void attn_mfma(
    const ushort* __restrict__ q,
    const ushort* __restrict__ k,
    const ushort* __restrict__ v,
    ushort* __restrict__ outf)
{
  __shared__ ushort sK [96 * APITCH];
  __shared__ ushort sVt[96 * APITCH];
  __shared__ ushort sP [6 * 16 * APITCH];

  const int tid  = threadIdx.x;
  const int lane = tid & 63;
  const int wv   = tid >> 6;
  const int l15  = lane & 15;
  const int lg   = lane >> 4;
  const long plane = (long)blockIdx.x * HW;

  for (int u = tid; u < 1152; u += 384) {
    int j = u / 12, c8 = u % 12;
    *(int4*)&sK[j * APITCH + c8 * 8] = *(const int4*)&k[plane + j * 96 + c8 * 8];
  }
  for (int u = tid; u < 1152; u += 384) {
    int j = u % 96, c8 = u / 96;
    ushort tmp[8];
    *(int4*)tmp = *(const int4*)&v[plane + j * 96 + c8 * 8];
#pragma unroll
    for (int e = 0; e < 8; ++e)
      sVt[(c8 * 8 + e) * APITCH + j] = tmp[e];
  }
  __syncthreads();

  const int i0 = wv * 16;

  bf16x8_t qf[3];
#pragma unroll
  for (int ks = 0; ks < 3; ++ks)
    qf[ks] = *(const bf16x8_t*)&q[plane + (i0 + l15) * 96 + ks * 32 + lg * 8];

  f32x4_t s[6];
#pragma unroll
  for (int jt = 0; jt < 6; ++jt) s[jt] = (f32x4_t){0.f, 0.f, 0.f, 0.f};
#pragma unroll
  for (int jt = 0; jt < 6; ++jt)
#pragma unroll
    for (int ks = 0; ks < 3; ++ks) {
      bf16x8_t kf = *(const bf16x8_t*)&sK[(jt * 16 + l15) * APITCH + ks * 32 + lg * 8];
      s[jt] = __builtin_amdgcn_mfma_f32_16x16x32_bf16(kf, qf[ks], s[jt], 0, 0, 0);
    }

  const float sc = 0.10206207261596575f;  // 1/sqrt(96)
  float m = -3.0e38f;
#pragma unroll
  for (int jt = 0; jt < 6; ++jt)
#pragma unroll
    for (int r = 0; r < 4; ++r) m = fmaxf(m, s[jt][r]);
  m = fmaxf(m, __shfl_xor(m, 16));
  m = fmaxf(m, __shfl_xor(m, 32));

  float p[6][4];
  float sum = 0.f;
#pragma unroll
  for (int jt = 0; jt < 6; ++jt)
#pragma unroll
    for (int r = 0; r < 4; ++r) {
      float e = __expf((s[jt][r] - m) * sc);
      p[jt][r] = e;
      sum += e;
    }
  sum += __shfl_xor(sum, 16);
  sum += __shfl_xor(sum, 32);
  const float inv = 1.f / sum;

  ushort* myP = &sP[wv * 16 * APITCH];
#pragma unroll
  for (int jt = 0; jt < 6; ++jt) {
    *(uint*)&myP[l15 * APITCH + jt * 16 + lg * 4] =
        pk2_bf16(p[jt][0] * inv, p[jt][1] * inv);
    *(uint*)&myP[l15 * APITCH + jt * 16 + lg * 4 + 2] =
        pk2_bf16(p[jt][2] * inv, p[jt][3] * inv);
  }

  bf16x8_t pf[3];
#pragma unroll
  for (int ks = 0; ks < 3; ++ks)
    pf[ks] = *(const bf16x8_t*)&myP[l15 * APITCH + ks * 32 + lg * 8];

  f32x4_t o[6];
#pragma unroll
  for (int wt = 0; wt < 6; ++wt) o[wt] = (f32x4_t){0.f, 0.f, 0.f, 0.f};
#pragma unroll
  for (int wt = 0; wt < 6; ++wt)
#pragma unroll
    for (int ks = 0; ks < 3; ++ks) {
      bf16x8_t vf = *(const bf16x8_t*)&sVt[(wt * 16 + l15) * APITCH + ks * 32 + lg * 8];
      o[wt] = __builtin_amdgcn_mfma_f32_16x16x32_bf16(pf[ks], vf, o[wt], 0, 0, 0);
    }

#pragma unroll
  for (int wt = 0; wt < 6; ++wt)
#pragma unroll
    for (int r = 0; r < 4; ++r) {
      int i = i0 + lg * 4 + r;
      outf[plane + i * 96 + wt * 16 + l15] =
          __bfloat16_as_ushort(__float2bfloat16(o[wt][r]));
    }
}

// ---------------------------------------------------------------------------
extern "C" void kernel_launch(void* const* d_in, const int* in_sizes, int n_in,
                              void* d_out, int out_size, void* d_ws, size_t ws_size,
                              hipStream_t stream) {
  (void)in_sizes; (void)n_in; (void)out_size; (void)ws_size;

  const float* feats = (const float*)d_in[0];
  const float* graph = (const float*)d_in[1];
  const float* wq    = (const float*)d_in[2];
  const float* bq    = (const float*)d_in[3];
  const float* wk    = (const float*)d_in[4];
  const float* bk    = (const float*)d_in[5];
  const float* wv    = (const float*)d_in[6];
  const float* bv    = (const float*)d_in[7];
  const float* wo    = (const float*)d_in[8];
  const float* bo    = (const float*)d_in[9];
  float* out = (float*)d_out;

  char* ws = (char*)d_ws;
  const long planeB   = PLANE_ELEMS * 2;                 // 37.75 MB per bf16 set
  const long pinElems = (long)BATCH * PAD * PAD * 256;   // padded NHWC elems
  ushort* qb   = (ushort*)ws;                            // q, then fused output
  ushort* kb   = (ushort*)(ws + planeB);
  ushort* vb   = (ushort*)(ws + 2 * planeB);
  ushort* pinF = (ushort*)(ws + 3 * planeB);             // feats NHWC (39.3MB)
  ushort* pinG = pinF + pinElems;                        // graph NHWC (39.3MB)
  ushort* wtq  = pinG + pinElems;
  ushort* wtk  = wtq + 9 * 256 * 256;
  ushort* wtv  = wtk + 9 * 256 * 256;
  ushort* wto  = wtv + 9 * 256 * 256;

  dim3 tgrid2(HW / 32, CH / 32, 2 * BATCH);  // (288, 8, 16)
  dim3 tgrid (HW / 32, CH / 32, BATCH);      // (288, 8, 8)
  dim3 agrid (BATCH * CH);

  prep_wb<<<9216 + 784, 256, 0, stream>>>(wq, wk, wv, wo, wtq, wtk, wtv, wto,
                                          pinF, pinG);

  nchw_f32_to_nhwc_bf16_2<<<tgrid2, 256, 0, stream>>>(feats, graph, pinF, pinG);

  // Fused K, V, Q convs: t=0 K(pinF), t=1 V(pinF), t=2 Q(pinG).
  conv3x3_mfma<3, ushort><<<3 * 768, 512, 0, stream>>>(
      pinF, pinG, wtk, wtv, wtq, bk, bv, bq, kb, vb, qb);

  attn_mfma<<<agrid, 384, 0, stream>>>(qb, kb, vb, qb);

  nchw_bf16_to_nhwc_bf16<<<tgrid, 256, 0, stream>>>(qb, pinF);

  conv3x3_mfma<1, float><<<768, 512, 0, stream>>>(
      pinF, pinF, wto, wto, wto, bo, bo, bo, out, out, out);
}

// Round 17
// 397.059 us; speedup vs baseline: 1.4960x; 1.4960x over previous
//
#include <hip/hip_runtime.h>
#include <hip/hip_bf16.h>

// Problem constants
constexpr int BATCH = 8;
constexpr int CH    = 256;
constexpr int H     = 96;
constexpr int W     = 96;
constexpr int HW    = H * W;                         // 9216
constexpr long PLANE_ELEMS = (long)BATCH * CH * HW;  // 18,874,368
constexpr int PAD   = 98;                            // padded spatial dim

typedef short  bf16x8_t __attribute__((ext_vector_type(8)));
typedef float  f32x4_t  __attribute__((ext_vector_type(4)));

__device__ inline uint pk2_bf16(float a, float b) {
  ushort lo = __bfloat16_as_ushort(__float2bfloat16(a));
  ushort hi = __bfloat16_as_ushort(__float2bfloat16(b));
  return (uint)lo | ((uint)hi << 16);
}

#define WAITVM(N) asm volatile("s_waitcnt vmcnt(" #N ")" ::: "memory")

__device__ __forceinline__ void gl_lds16(const ushort* g, ushort* l) {
  __builtin_amdgcn_global_load_lds(
      (const __attribute__((address_space(1))) void*)g,
      (__attribute__((address_space(3))) void*)l, 16, 0, 0);
}

// ---------------------------------------------------------------------------
// Fused prep: weights (4 tensors OIHW f32 -> fragment-linear bf16) + border
// zeroing of the two padded NHWC buffers.
// Weight layout: idx = ((((tap*8+cc)*16+q)*16+l15)*4+lg)*8+e,
//   co = q*16+l15, ci = cc*32+lg*8+e  -> A-fragment load = contiguous 1KB.
// ---------------------------------------------------------------------------
__global__ __launch_bounds__(256) void prep_wb(
    const float* __restrict__ s0, const float* __restrict__ s1,
    const float* __restrict__ s2, const float* __restrict__ s3,
    ushort* __restrict__ d0, ushort* __restrict__ d1,
    ushort* __restrict__ d2, ushort* __restrict__ d3,
    ushort* __restrict__ p0, ushort* __restrict__ p1)
{
  if (blockIdx.x < 9216) {
    const int t = blockIdx.x / 2304;
    const int idx = (blockIdx.x % 2304) * 256 + threadIdx.x;
    const float* s = (t == 0) ? s0 : (t == 1) ? s1 : (t == 2) ? s2 : s3;
    ushort* d      = (t == 0) ? d0 : (t == 1) ? d1 : (t == 2) ? d2 : d3;
    const int e   = idx & 7;
    const int lg  = (idx >> 3) & 3;
    const int l15 = (idx >> 5) & 15;
    const int q   = (idx >> 9) & 15;
    const int cc  = (idx >> 13) & 7;
    const int tap = idx >> 16;
    const int co  = q * 16 + l15;
    const int ci  = cc * 32 + lg * 8 + e;
    d[idx] = __bfloat16_as_ushort(__float2bfloat16(s[(co * 256 + ci) * 9 + tap]));
    return;
  }
  const int bb = blockIdx.x - 9216;        // 0..783 = (49 u-blocks, 8 b, 2 t)
  const int ub = bb % 49;
  const int b  = (bb / 49) & 7;
  ushort* p = (bb >= 392) ? p1 : p0;
  const int u = ub * 256 + threadIdx.x;
  if (u >= 12416) return;
  int y, x, cu;
  if (u < 6272)      { y = (u < 3136) ? 0 : 97; int r = u % 3136; x = r >> 5; cu = r & 31; }
  else               { int r = u - 6272; x = (r < 3072) ? 0 : 97; int r2 = r % 3072; y = 1 + (r2 >> 5); cu = r2 & 31; }
  int4 z = make_int4(0, 0, 0, 0);
  *(int4*)&p[(((long)b * PAD + y) * PAD + x) * 256 + cu * 8] = z;
}

// ---------------------------------------------------------------------------
// Fused NCHW fp32 -> padded NHWC bf16 for feats & graph.
// grid (288, 8, 16): z>>3 selects tensor, z&7 = batch.
// ---------------------------------------------------------------------------
__global__ __launch_bounds__(256) void nchw_f32_to_nhwc_bf16_2(
    const float* __restrict__ in0, const float* __restrict__ in1,
    ushort* __restrict__ out0, ushort* __restrict__ out1)
{
  __shared__ float t[32][33];
  const int tid = threadIdx.x;
  const int p0 = blockIdx.x * 32;
  const int c0 = blockIdx.y * 32;
  const int ts = blockIdx.z >> 3;
  const int b  = blockIdx.z & 7;
  const float* in = ts ? in1 : in0;
  ushort* out     = ts ? out1 : out0;
  const int tp = tid & 31, tc8 = tid >> 5;
#pragma unroll
  for (int i = 0; i < 4; ++i) {
    int c = tc8 + i * 8;
    t[c][tp] = in[((long)(b * 256 + c0 + c)) * HW + p0 + tp];
  }
  __syncthreads();
  const int wc = tid & 31, wp8 = tid >> 5;
#pragma unroll
  for (int i = 0; i < 4; ++i) {
    int p = p0 + wp8 + i * 8;
    int y = p / 96, x = p % 96;
    out[(((long)b * PAD + y + 1) * PAD + x + 1) * 256 + c0 + wc] =
        __bfloat16_as_ushort(__float2bfloat16(t[wc][wp8 + i * 8]));
  }
}

// ---------------------------------------------------------------------------
// NCHW bf16 -> padded NHWC bf16 (fused attention output feeding conv O).
// ---------------------------------------------------------------------------
__global__ __launch_bounds__(256) void nchw_bf16_to_nhwc_bf16(
    const ushort* __restrict__ in, ushort* __restrict__ out)
{
  __shared__ ushort t[32][34];
  const int tid = threadIdx.x;
  const int p0 = blockIdx.x * 32;
  const int c0 = blockIdx.y * 32;
  const int b  = blockIdx.z;
  const int tp = tid & 31, tc8 = tid >> 5;
#pragma unroll
  for (int i = 0; i < 4; ++i) {
    int c = tc8 + i * 8;
    t[c][tp] = in[((long)(b * 256 + c0 + c)) * HW + p0 + tp];
  }
  __syncthreads();
  const int wc = tid & 31, wp8 = tid >> 5;
#pragma unroll
  for (int i = 0; i < 4; ++i) {
    int p = p0 + wp8 + i * 8;
    int y = p / 96, x = p % 96;
    out[(((long)b * PAD + y + 1) * PAD + x + 1) * 256 + c0 + wc] = t[wc][wp8 + i * 8];
  }
}

// ---------------------------------------------------------------------------
// Conv 3x3 SAME via bf16 MFMA — R11 structure (the converged optimum):
// launch_bounds(256,2); wave = (wm co-half, wn row); m=4, n=6.
// A: per-wave coalesced global->register (fragment-linear), 3-slot rotation,
// 2-tap lead, compiler-tracked waits, no per-tap barrier.
// B: gl_lds double-buffered; IN(c+1) issued at loop head (buffer freed by
// preceding barrier). Boundary ledger: FIFO = [IN x7][A(c,2..8)+A(c+1,0..1)
// = 36] -> WAITVM(36) drains IN, keeps A in flight.
// Constraint map (17 rounds): 128 arch-VGPR cap at 2 blk/CU forbids extra
// live state (R9/R10/R12/R13/R15 spilled); 1 blk/CU kills barrier overlap
// (R16, -50%); 32x32 shape neutral (R14). This is the structural floor.
// ---------------------------------------------------------------------------
template <int NT, typename OutT>
__global__ __launch_bounds__(256, 2) void conv3x3_mfma(
    const ushort* pin0, const ushort* pin1,
    const ushort* w0, const ushort* w1, const ushort* w2,
    const float* bias0, const float* bias1, const float* bias2,
    OutT* o0, OutT* o1, OutT* o2)
{
  const int tid  = threadIdx.x;
  const int lane = tid & 63;
  const int wv   = tid >> 6;
  const int wm   = wv & 1;        // co half (64 co)
  const int wn   = wv >> 1;       // row within 2-row tile
  const int l15  = lane & 15;
  const int lg   = lane >> 4;

  // Bijective XCD swizzle over NT*768 blocks (divisible by 8).
  const int nwg = NT * 768;
  const int cpx = nwg >> 3;
  const int swz = ((int)blockIdx.x & 7) * cpx + ((int)blockIdx.x >> 3);
  const int t    = swz / 768;
  const int rest = swz % 768;
  const ushort* pin = (t == 2) ? pin1 : pin0;
  const ushort* wt  = (t == 0) ? w0 : (t == 1) ? w1 : w2;
  const float* bias = (t == 0) ? bias0 : (t == 1) ? bias1 : bias2;
  OutT* out         = (t == 0) ? o0 : (t == 1) ? o1 : o2;

  const int cox = rest & 1;
  const int yb  = (rest >> 1) % 48;
  const int b   = (rest >> 1) / 48;
  const int co0 = cox * 128;
  const int y0  = yb * 2;
  const int coq = cox * 8 + wm * 4;       // co/16 fragment base for this wave
  const int alo = (l15 * 4 + lg) << 3;    // per-lane elem offset in A fragment

  __shared__ ushort sIn[2][1568 * 8];     // 2 x 25,088 B (4rr x 98xx x 32ci)

  f32x4_t acc[4][6];
#pragma unroll
  for (int m = 0; m < 4; ++m)
#pragma unroll
    for (int n = 0; n < 6; ++n)
      acc[m][n] = (f32x4_t){0.f, 0.f, 0.f, 0.f};

  // Stage packed 25KB input tile (ci-chunk cc) into buf cc&1 via gl_lds.
  auto issueIN = [&](int cc) {
    const int ci0 = cc * 32;
    const int ubase = wv * 392;
#pragma unroll
    for (int it = 0; it < 7; ++it) {
      int lo = it * 64 + lane;
      if (lo < 392) {
        int u  = ubase + lo;
        int q  = u >> 2;
        int g  = u & 3;
        int xx = q % 98, rr = q / 98;
        int ug = g ^ ((xx + (xx >> 2)) & 3);        // pre-swizzled source
        const ushort* src = pin + (((long)(b * PAD + y0 + rr)) * PAD + xx) * 256 + ci0 + ug * 8;
        ushort* dst = (ushort*)((char*)&sIn[cc & 1][0] + (long)u * 16);
        gl_lds16(src, dst);
      }
    }
  };

  // Coalesced A-fragment register load (L1/L2-resident weights).
  auto glda = [&](int tap, int cc, int m) -> bf16x8_t {
    return *(const bf16x8_t*)&wt[(((tap * 8 + cc) * 16 + coq + m) << 9) + alo];
  };

  bf16x8_t a0[4], a1[4], a2[4];   // 3-slot rotation; tap t consumes slot t%3

#define ISSUE_A(CC, TAP, AR)                \
  if ((CC) < 8) {                           \
    AR[0] = glda((TAP), (CC), 0);           \
    AR[1] = glda((TAP), (CC), 1);           \
    AR[2] = glda((TAP), (CC), 2);           \
    AR[3] = glda((TAP), (CC), 3);           \
  }

  auto dotap = [&](int DY, int DX, int bi, const bf16x8_t* a) {
    bf16x8_t bb[6];
    const char* Bb = (const char*)&sIn[bi][0];
    const int s    = l15 + DX;
    const int boff = (lg ^ ((s + (s >> 2)) & 3)) << 4;   // swizzled read
    const int rr   = wn + DY;
#pragma unroll
    for (int n = 0; n < 6; ++n)
      bb[n] = *(const bf16x8_t*)(Bb + ((rr * 98 + n * 16 + s) << 6) + boff);
    __builtin_amdgcn_s_setprio(1);
#pragma unroll
    for (int m = 0; m < 4; ++m)
#pragma unroll
      for (int n = 0; n < 6; ++n)
        acc[m][n] = __builtin_amdgcn_mfma_f32_16x16x32_bf16(
            a[m], bb[n], acc[m][n], 0, 0, 0);
    __builtin_amdgcn_s_setprio(0);
  };

  // Prologue: IN(0) [7] then A(0,0),A(0,1) [8] -> WAITVM(8) drains IN only.
  issueIN(0);
  __builtin_amdgcn_sched_barrier(0);
  ISSUE_A(0, 0, a0);
  ISSUE_A(0, 1, a1);
  __builtin_amdgcn_sched_barrier(0);
  WAITVM(8);
  __builtin_amdgcn_s_barrier();
  __builtin_amdgcn_sched_barrier(0);

#pragma unroll 1
  for (int c = 0; c < 8; ++c) {
    const int bi = c & 1;
    // Full-chunk-early IN prefetch (register-neutral: gl_lds holds no VGPRs).
    if (c < 7) issueIN(c + 1);
    __builtin_amdgcn_sched_barrier(0);
    // Taps flow barrier-free: A deps are register loads (compiler-tracked),
    // B deps are lgkmcnt ds_reads on a chunk-stable buffer.
    ISSUE_A(c, 2, a2)  dotap(0, 0, bi, a0);
    ISSUE_A(c, 3, a0)  dotap(0, 1, bi, a1);
    ISSUE_A(c, 4, a1)  dotap(0, 2, bi, a2);
    ISSUE_A(c, 5, a2)  dotap(1, 0, bi, a0);
    ISSUE_A(c, 6, a0)  dotap(1, 1, bi, a1);
    ISSUE_A(c, 7, a1)  dotap(1, 2, bi, a2);
    ISSUE_A(c, 8, a2)  dotap(2, 0, bi, a0);
    ISSUE_A(c + 1, 0, a0)  dotap(2, 1, bi, a1);
    ISSUE_A(c + 1, 1, a1)  dotap(2, 2, bi, a2);
    __builtin_amdgcn_sched_barrier(0);
    // Ledger: FIFO = [IN(c+1) x7][A(c,2..8)=28][A(c+1,0..1)=8] -> 36 A's.
    if (c < 7) { WAITVM(36); } else { WAITVM(0); }
    __builtin_amdgcn_s_barrier();     // all waves' IN writes visible
    __builtin_amdgcn_sched_barrier(0);
  }
#undef ISSUE_A

  // Epilogue. C/D layout: col = lane&15 -> pixel, row -> co.
  if constexpr (sizeof(OutT) == 2) {
    // bf16: LDS-bounce -> coalesced 16B stores. Two 64-co halves (h == wm).
    char* sE = (char*)&sIn[0][0];          // 64 rows x 400B pitch = 25.6KB
#pragma unroll
    for (int h = 0; h < 2; ++h) {
      if (wm == h) {
#pragma unroll
        for (int m = 0; m < 4; ++m)
#pragma unroll
          for (int r = 0; r < 4; ++r) {
            const int col = m * 16 + lg * 4 + r;           // co within half
            const float bv = bias[co0 + h * 64 + col];
#pragma unroll
            for (int n = 0; n < 6; ++n) {
              *(ushort*)(sE + col * 400 + (wn * 96 + n * 16 + l15) * 2) =
                  __bfloat16_as_ushort(__float2bfloat16(acc[m][n][r] + bv));
            }
          }
      }
      __syncthreads();
#pragma unroll
      for (int it = 0; it < 7; ++it) {
        int u = it * 256 + tid;
        if (u < 1600) {
          int co = u / 25, ru = u % 25;
          if (ru < 24) {
            int4 v = *(const int4*)(sE + co * 400 + ru * 16);
            int e0 = ru * 8;
            int yy = y0 + (e0 >= 96);
            int x  = e0 - (e0 >= 96 ? 96 : 0);
            *(int4*)&out[(((long)(b * 256 + co0 + h * 64 + co)) * 96 + yy) * 96 + x] = v;
          }
        }
      }
      __syncthreads();
    }
  } else {
    // f32: LDS-bounce (direct 64B stores showed 2x write amplification).
    char* sE = (char*)&sIn[0][0];          // 64 co x pitch 196 f32 = 50,176 B
#pragma unroll
    for (int h = 0; h < 2; ++h) {
      if (wm == h) {
#pragma unroll
        for (int m = 0; m < 4; ++m)
#pragma unroll
          for (int r = 0; r < 4; ++r) {
            const int col = m * 16 + lg * 4 + r;
            const float bv = bias[co0 + h * 64 + col];
#pragma unroll
            for (int n = 0; n < 6; ++n) {
              *(float*)(sE + (col * 196 + wn * 96 + n * 16 + l15) * 4) =
                  acc[m][n][r] + bv;
            }
          }
      }
      __syncthreads();
#pragma unroll
      for (int it = 0; it < 12; ++it) {
        int u = it * 256 + tid;
        int co = u / 48, ru = u % 48;
        int4 v = *(const int4*)(sE + (co * 196 + ru * 4) * 4);
        int e0 = ru * 4;
        int yy = y0 + (e0 >= 96);
        int x  = e0 - (e0 >= 96 ? 96 : 0);
        *(int4*)&out[(((long)(b * 256 + co0 + h * 64 + co)) * 96 + yy) * 96 + x] = v;
      }
      __syncthreads();
    }
  }
}

// ---------------------------------------------------------------------------
// MFMA row attention. One block (384 thr = 6 waves) per (b,c) plane.
// ---------------------------------------------------------------------------
constexpr int APITCH = 104;

__global__ __launch_bounds__(384, 3) void attn_mfma(
    const ushort* __restrict__ q,
    const ushort* __restrict__ k,
    const ushort* __restrict__ v,
    ushort* __restrict__ outf)
{
  __shared__ ushort sK [96 * APITCH];
  __shared__ ushort sVt[96 * APITCH];
  __shared__ ushort sP [6 * 16 * APITCH];

  const int tid  = threadIdx.x;
  const int lane = tid & 63;
  const int wv   = tid >> 6;
  const int l15  = lane & 15;
  const int lg   = lane >> 4;
  const long plane = (long)blockIdx.x * HW;

  for (int u = tid; u < 1152; u += 384) {
    int j = u / 12, c8 = u % 12;
    *(int4*)&sK[j * APITCH + c8 * 8] = *(const int4*)&k[plane + j * 96 + c8 * 8];
  }
  for (int u = tid; u < 1152; u += 384) {
    int j = u % 96, c8 = u / 96;
    ushort tmp[8];
    *(int4*)tmp = *(const int4*)&v[plane + j * 96 + c8 * 8];
#pragma unroll
    for (int e = 0; e < 8; ++e)
      sVt[(c8 * 8 + e) * APITCH + j] = tmp[e];
  }
  __syncthreads();

  const int i0 = wv * 16;

  bf16x8_t qf[3];
#pragma unroll
  for (int ks = 0; ks < 3; ++ks)
    qf[ks] = *(const bf16x8_t*)&q[plane + (i0 + l15) * 96 + ks * 32 + lg * 8];

  f32x4_t s[6];
#pragma unroll
  for (int jt = 0; jt < 6; ++jt) s[jt] = (f32x4_t){0.f, 0.f, 0.f, 0.f};
#pragma unroll
  for (int jt = 0; jt < 6; ++jt)
#pragma unroll
    for (int ks = 0; ks < 3; ++ks) {
      bf16x8_t kf = *(const bf16x8_t*)&sK[(jt * 16 + l15) * APITCH + ks * 32 + lg * 8];
      s[jt] = __builtin_amdgcn_mfma_f32_16x16x32_bf16(kf, qf[ks], s[jt], 0, 0, 0);
    }

  const float sc = 0.10206207261596575f;  // 1/sqrt(96)
  float m = -3.0e38f;
#pragma unroll
  for (int jt = 0; jt < 6; ++jt)
#pragma unroll
    for (int r = 0; r < 4; ++r) m = fmaxf(m, s[jt][r]);
  m = fmaxf(m, __shfl_xor(m, 16));
  m = fmaxf(m, __shfl_xor(m, 32));

  float p[6][4];
  float sum = 0.f;
#pragma unroll
  for (int jt = 0; jt < 6; ++jt)
#pragma unroll
    for (int r = 0; r < 4; ++r) {
      float e = __expf((s[jt][r] - m) * sc);
      p[jt][r] = e;
      sum += e;
    }
  sum += __shfl_xor(sum, 16);
  sum += __shfl_xor(sum, 32);
  const float inv = 1.f / sum;

  ushort* myP = &sP[wv * 16 * APITCH];
#pragma unroll
  for (int jt = 0; jt < 6; ++jt) {
    *(uint*)&myP[l15 * APITCH + jt * 16 + lg * 4] =
        pk2_bf16(p[jt][0] * inv, p[jt][1] * inv);
    *(uint*)&myP[l15 * APITCH + jt * 16 + lg * 4 + 2] =
        pk2_bf16(p[jt][2] * inv, p[jt][3] * inv);
  }

  bf16x8_t pf[3];
#pragma unroll
  for (int ks = 0; ks < 3; ++ks)
    pf[ks] = *(const bf16x8_t*)&myP[l15 * APITCH + ks * 32 + lg * 8];

  f32x4_t o[6];
#pragma unroll
  for (int wt = 0; wt < 6; ++wt) o[wt] = (f32x4_t){0.f, 0.f, 0.f, 0.f};
#pragma unroll
  for (int wt = 0; wt < 6; ++wt)
#pragma unroll
    for (int ks = 0; ks < 3; ++ks) {
      bf16x8_t vf = *(const bf16x8_t*)&sVt[(wt * 16 + l15) * APITCH + ks * 32 + lg * 8];
      o[wt] = __builtin_amdgcn_mfma_f32_16x16x32_bf16(pf[ks], vf, o[wt], 0, 0, 0);
    }

#pragma unroll
  for (int wt = 0; wt < 6; ++wt)
#pragma unroll
    for (int r = 0; r < 4; ++r) {
      int i = i0 + lg * 4 + r;
      outf[plane + i * 96 + wt * 16 + l15] =
          __bfloat16_as_ushort(__float2bfloat16(o[wt][r]));
    }
}

// ---------------------------------------------------------------------------
extern "C" void kernel_launch(void* const* d_in, const int* in_sizes, int n_in,
                              void* d_out, int out_size, void* d_ws, size_t ws_size,
                              hipStream_t stream) {
  (void)in_sizes; (void)n_in; (void)out_size; (void)ws_size;

  const float* feats = (const float*)d_in[0];
  const float* graph = (const float*)d_in[1];
  const float* wq    = (const float*)d_in[2];
  const float* bq    = (const float*)d_in[3];
  const float* wk    = (const float*)d_in[4];
  const float* bk    = (const float*)d_in[5];
  const float* wv    = (const float*)d_in[6];
  const float* bv    = (const float*)d_in[7];
  const float* wo    = (const float*)d_in[8];
  const float* bo    = (const float*)d_in[9];
  float* out = (float*)d_out;

  char* ws = (char*)d_ws;
  const long planeB   = PLANE_ELEMS * 2;                 // 37.75 MB per bf16 set
  const long pinElems = (long)BATCH * PAD * PAD * 256;   // padded NHWC elems
  ushort* qb   = (ushort*)ws;                            // q, then fused output
  ushort* kb   = (ushort*)(ws + planeB);
  ushort* vb   = (ushort*)(ws + 2 * planeB);
  ushort* pinF = (ushort*)(ws + 3 * planeB);             // feats NHWC (39.3MB)
  ushort* pinG = pinF + pinElems;                        // graph NHWC (39.3MB)
  ushort* wtq  = pinG + pinElems;
  ushort* wtk  = wtq + 9 * 256 * 256;
  ushort* wtv  = wtk + 9 * 256 * 256;
  ushort* wto  = wtv + 9 * 256 * 256;

  dim3 tgrid2(HW / 32, CH / 32, 2 * BATCH);  // (288, 8, 16)
  dim3 tgrid (HW / 32, CH / 32, BATCH);      // (288, 8, 8)
  dim3 agrid (BATCH * CH);

  prep_wb<<<9216 + 784, 256, 0, stream>>>(wq, wk, wv, wo, wtq, wtk, wtv, wto,
                                          pinF, pinG);

  nchw_f32_to_nhwc_bf16_2<<<tgrid2, 256, 0, stream>>>(feats, graph, pinF, pinG);

  // Fused K, V, Q convs: t=0 K(pinF), t=1 V(pinF), t=2 Q(pinG).
  conv3x3_mfma<3, ushort><<<3 * 768, 256, 0, stream>>>(
      pinF, pinG, wtk, wtv, wtq, bk, bv, bq, kb, vb, qb);

  attn_mfma<<<agrid, 384, 0, stream>>>(qb, kb, vb, qb);

  nchw_bf16_to_nhwc_bf16<<<tgrid, 256, 0, stream>>>(qb, pinF);

  conv3x3_mfma<1, float><<<768, 256, 0, stream>>>(
      pinF, pinF, wto, wto, wto, bo, bo, bo, out, out, out);
}